// Round 5
// baseline (154.944 us; speedup 1.0000x reference)
//
#include <hip/hip_runtime.h>
#include <stdint.h>

#define U 128
#define V 128
#define IN_STRIDE 512
#define OUT_STRIDE 512
#define W_STRIDE (8 * U * V) /* 131072 floats per expert */
#define NB 32768
#define MAXTILES 1027        /* sum ceil(cnt_e/32) <= 1024+3 */

// Workspace layout (bytes)
#define WS_WSHUF 0                          // 1 MB: bf16 weights in B-fragment layout
#define WS_PERM  (1 << 20)                  // int[4*32768] padded per-expert regions
#define WS_CURS  ((1 << 20) + (1 << 19))    // int[4] cursors (= per-expert counts)
#define WS_XSHUF (2 << 20)                  // 1027 tiles * 16384 shorts * 2B = 33.7 MB
// total ws use ~= 35.7 MB

typedef __bf16 bf16x8 __attribute__((ext_vector_type(8)));
typedef float f32x16 __attribute__((ext_vector_type(16)));
typedef unsigned int u32x4 __attribute__((ext_vector_type(4)));

static __device__ __forceinline__ unsigned short f2bf(float f) {
    unsigned int u = __builtin_bit_cast(unsigned int, f);
    u += 0x7FFFu + ((u >> 16) & 1u);   // round-to-nearest-even
    return (unsigned short)(u >> 16);
}

// tile g -> (expert e, rows in tile, perm base). e = -1 if g >= ntot.
static __device__ __forceinline__ void tile_map(int g, int c0, int c1, int c2, int c3,
                                                int& e, int& rows, int& tbase) {
    int cs[4] = {c0, c1, c2, c3};
    int acc = 0; e = -1; rows = 0; tbase = 0;
#pragma unroll
    for (int i = 0; i < 4; i++) {
        int te = (cs[i] + 31) >> 5;
        if (e < 0 && g < acc + te) {
            e = i;
            int tile = g - acc;
            rows = cs[i] - tile * 32;
            if (rows > 32) rows = 32;
            tbase = i * NB + tile * 32;
        }
        acc += te;
    }
}

// ---------------------------------------------------------------------------
// fused prep (proven in R2-R3):
//  blocks [0,256): weights fp32 -> bf16, MFMA B-fragment layout
//   flat short idx = ((((e*8+s)*4+nt)*8+kt)*64+lane)*8 + j
//   element = W[e][s][k = kt*16+(lane>>5)*8+j][n = nt*32+(lane&31)], segs 4..7 x0.5
//  blocks [256,384): counting-scatter row ids into padded per-expert perm regions.
// ---------------------------------------------------------------------------
__global__ void prep_kernel(const float* __restrict__ w, const int* __restrict__ wid,
                            unsigned short* __restrict__ wshuf, int* __restrict__ cursors,
                            int* __restrict__ perm) {
    int blk = blockIdx.x;
    if (blk < 256) {
        int t = blk * 256 + threadIdx.x;      // 0..65535
        int lane = t & 63;
        int kt = (t >> 6) & 7;
        int nt = (t >> 9) & 3;
        int s  = (t >> 11) & 7;
        int e  = (t >> 14) & 3;
        int kbase = kt * 16 + ((lane >> 5) << 3);
        int n = nt * 32 + (lane & 31);
        const float* src = w + (size_t)e * W_STRIDE + (size_t)s * (U * V) + n;
        float sc = (s >= 4) ? 0.5f : 1.0f;
        __attribute__((aligned(16))) unsigned short o[8];
#pragma unroll
        for (int j = 0; j < 8; j++) o[j] = f2bf(src[(size_t)(kbase + j) * V] * sc);
        *(u32x4*)(wshuf + (size_t)t * 8) = *(const u32x4*)o;
    } else {
        __shared__ int lcnt[4], lbase[4];
        int tid = threadIdx.x;
        if (tid < 4) lcnt[tid] = 0;
        __syncthreads();
        int b = (blk - 256) * 256 + tid;   // < 32768
        int e = wid[b];
        int r = atomicAdd(&lcnt[e], 1);
        __syncthreads();
        if (tid < 4) lbase[tid] = atomicAdd(&cursors[tid], lcnt[tid]);
        __syncthreads();
        perm[e * NB + lbase[e] + r] = b;
    }
}

// ---------------------------------------------------------------------------
// xshuf: gather sorted rows, fp32 -> bf16, into MFMA A-fragment layout.
//  flat short idx = (((tile*32 + ktile)*64 + lane)*8 + j)
//  element = x[perm[tbase + (lane&31)]][ktile*16 + (lane>>5)*8 + j]
// Padding lanes (row >= rows) and tiles >= ntot write zeros (A rows of zero
// are harmless; gemm store guard handles them).
// Writes are perfectly coalesced 16 B/lane streams.
// ---------------------------------------------------------------------------
__global__ __launch_bounds__(256, 4) void xshuf_kernel(
        const float* __restrict__ x, const int* __restrict__ perm,
        const int* __restrict__ cursors, unsigned short* __restrict__ xshuf) {
    int t = blockIdx.x * 256 + threadIdx.x;   // < 1027*2048 = 2,103,296
    int tile = t >> 11;
    int rem = t & 2047;
    int ktile = rem >> 6;      // 0..31
    int lane = rem & 63;
    int c0 = cursors[0], c1 = cursors[1], c2 = cursors[2], c3 = cursors[3];
    int e, rows, tbase;
    tile_map(tile, c0, c1, c2, c3, e, rows, tbase);
    int m = lane & 31;
    __attribute__((aligned(16))) unsigned short o[8] = {0, 0, 0, 0, 0, 0, 0, 0};
    if (e >= 0 && m < rows) {
        int row = perm[tbase + m];
        const float* p = x + (size_t)row * IN_STRIDE + ktile * 16 + ((lane >> 5) << 3);
        float4 v0 = *(const float4*)p;
        float4 v1 = *(const float4*)(p + 4);
        o[0] = f2bf(v0.x); o[1] = f2bf(v0.y); o[2] = f2bf(v0.z); o[3] = f2bf(v0.w);
        o[4] = f2bf(v1.x); o[5] = f2bf(v1.y); o[6] = f2bf(v1.z); o[7] = f2bf(v1.w);
    }
    *(u32x4*)(xshuf + (size_t)t * 8) = *(const u32x4*)o;
}

// ---------------------------------------------------------------------------
// gemm R5: barrier-free, no LDS. Block = 256 thr = 4 waves = 1 sorted 32-row
// tile (single expert). Wave w = kout (out block), covers all 128 out cols
// (4 ntiles, 4 f32x16 accs). K = 256: x-block kout (seg kout) ++
// x-block (kout+3)&3 (seg +4, 0.5 pre-folded into wshuf).
// A: 1 coalesced dwordx4 per k-step from xshuf (L3-hot).
// B: 4 coalesced dwordx4 per k-step from wshuf (1 MB, L2-hot).
// No __syncthreads anywhere: waves pipeline loads/MFMA/stores independently.
// ---------------------------------------------------------------------------
__global__ __launch_bounds__(256, 4) void gemm_kernel(
        const unsigned short* __restrict__ xshuf, const unsigned short* __restrict__ wshuf,
        const int* __restrict__ cursors, const int* __restrict__ perm,
        float* __restrict__ out) {
    int c0 = cursors[0], c1 = cursors[1], c2 = cursors[2], c3 = cursors[3];
    int g = blockIdx.x;
    int e, rows, tbase;
    tile_map(g, c0, c1, c2, c3, e, rows, tbase);
    if (e < 0) return;

    const int t = threadIdx.x;
    const int kout = t >> 6;        // wave id = out block
    const int lane = t & 63;
    const int m0 = lane & 31;

    const unsigned short* xs = xshuf + (size_t)g * 16384;   // this tile's A fragments

    f32x16 acc0 = {}, acc1 = {}, acc2 = {}, acc3 = {};

    const int xb0 = kout, sg0 = kout;
    const int xb1 = (kout + 3) & 3, sg1 = xb1 + 4;
    int xbs[2] = {xb0, xb1};
    int sgs[2] = {sg0, sg1};

#pragma unroll
    for (int c = 0; c < 2; c++) {
        const unsigned short* wbase = wshuf + (size_t)(e * 8 + sgs[c]) * 16384;
        const int Kbase = xbs[c] * 8;
#pragma unroll
        for (int kt = 0; kt < 8; kt++) {
            bf16x8 a = __builtin_bit_cast(bf16x8,
                *(const u32x4*)(xs + ((size_t)(Kbase + kt) * 64 + lane) * 8));
            bf16x8 b0 = __builtin_bit_cast(bf16x8,
                *(const u32x4*)(wbase + ((size_t)(0 * 8 + kt) * 64 + lane) * 8));
            bf16x8 b1 = __builtin_bit_cast(bf16x8,
                *(const u32x4*)(wbase + ((size_t)(1 * 8 + kt) * 64 + lane) * 8));
            bf16x8 b2 = __builtin_bit_cast(bf16x8,
                *(const u32x4*)(wbase + ((size_t)(2 * 8 + kt) * 64 + lane) * 8));
            bf16x8 b3 = __builtin_bit_cast(bf16x8,
                *(const u32x4*)(wbase + ((size_t)(3 * 8 + kt) * 64 + lane) * 8));
            acc0 = __builtin_amdgcn_mfma_f32_32x32x16_bf16(a, b0, acc0, 0, 0, 0);
            acc1 = __builtin_amdgcn_mfma_f32_32x32x16_bf16(a, b1, acc1, 0, 0, 0);
            acc2 = __builtin_amdgcn_mfma_f32_32x32x16_bf16(a, b2, acc2, 0, 0, 0);
            acc3 = __builtin_amdgcn_mfma_f32_32x32x16_bf16(a, b3, acc3, 0, 0, 0);
        }
    }

    // epilogue: C/D layout col=lane&31, row=(reg&3)+8*(reg>>2)+4*(lane>>5)
    const int rh = (lane >> 5) << 2;
    const int colb = kout * 128 + m0;
#pragma unroll
    for (int q = 0; q < 4; q++) {
#pragma unroll
        for (int d = 0; d < 4; d++) {
            int rl = d + 8 * q + rh;
            if (rl < rows) {
                int rg = perm[tbase + rl];
                float* o = out + (size_t)rg * OUT_STRIDE + colb;
                int reg = q * 4 + d;
                o[0]  = acc0[reg];
                o[32] = acc1[reg];
                o[64] = acc2[reg];
                o[96] = acc3[reg];
            }
        }
    }
}

extern "C" void kernel_launch(void* const* d_in, const int* in_sizes, int n_in,
                              void* d_out, int out_size, void* d_ws, size_t ws_size,
                              hipStream_t stream) {
    const float* x = (const float*)d_in[0];
    const float* w = (const float*)d_in[1];
    const int* wid = (const int*)d_in[2];
    float* out = (float*)d_out;

    char* ws = (char*)d_ws;
    unsigned short* wshuf = (unsigned short*)(ws + WS_WSHUF);
    int* perm = (int*)(ws + WS_PERM);
    int* cursors = (int*)(ws + WS_CURS);
    unsigned short* xshuf = (unsigned short*)(ws + WS_XSHUF);

    hipMemsetAsync(cursors, 0, 16, stream);
    prep_kernel<<<384, 256, 0, stream>>>(w, wid, wshuf, cursors, perm);
    xshuf_kernel<<<MAXTILES * 8, 256, 0, stream>>>(x, perm, cursors, xshuf);
    gemm_kernel<<<MAXTILES, 256, 0, stream>>>(xshuf, wshuf, cursors, perm, out);
}

// Round 6
// 154.453 us; speedup vs baseline: 1.0032x; 1.0032x over previous
//
#include <hip/hip_runtime.h>
#include <stdint.h>

#define U 128
#define V 128
#define IN_STRIDE 512
#define OUT_STRIDE 512
#define W_STRIDE (8 * U * V) /* 131072 floats per expert */
#define NB 32768
#define MAXTILES 1027        /* sum ceil(cnt_e/32) <= 1024+3 */

// Workspace layout (bytes)
#define WS_WSHUF 0                          // 1 MB: bf16 weights in B-fragment layout
#define WS_PERM  (1 << 20)                  // int[4*32768] padded per-expert regions
#define WS_CURS  ((1 << 20) + (1 << 19))    // int[4] cursors (= per-expert counts)

typedef __bf16 bf16x8 __attribute__((ext_vector_type(8)));
typedef float f32x16 __attribute__((ext_vector_type(16)));
typedef unsigned int u32x4 __attribute__((ext_vector_type(4)));

static __device__ __forceinline__ unsigned short f2bf(float f) {
    unsigned int u = __builtin_bit_cast(unsigned int, f);
    u += 0x7FFFu + ((u >> 16) & 1u);   // round-to-nearest-even
    return (unsigned short)(u >> 16);
}

// tile g -> (expert e, rows in tile, perm base). e = -1 if g >= ntot.
static __device__ __forceinline__ void tile_map(int g, int c0, int c1, int c2, int c3,
                                                int& e, int& rows, int& tbase) {
    int cs[4] = {c0, c1, c2, c3};
    int acc = 0; e = -1; rows = 0; tbase = 0;
#pragma unroll
    for (int i = 0; i < 4; i++) {
        int te = (cs[i] + 31) >> 5;
        if (e < 0 && g < acc + te) {
            e = i;
            int tile = g - acc;
            rows = cs[i] - tile * 32;
            if (rows > 32) rows = 32;
            tbase = i * NB + tile * 32;
        }
        acc += te;
    }
}

// ---------------------------------------------------------------------------
// fused prep (proven R2-R5):
//  blocks [0,256): weights fp32 -> bf16, MFMA B-fragment layout
//   flat short idx = ((((e*8+s)*4+nt)*8+kt)*64+lane)*8 + j
//   element = W[e][s][k = kt*16+(lane>>5)*8+j][n = nt*32+(lane&31)], segs 4..7 x0.5
//  blocks [256,384): counting-scatter row ids into padded per-expert perm regions.
// ---------------------------------------------------------------------------
__global__ void prep_kernel(const float* __restrict__ w, const int* __restrict__ wid,
                            unsigned short* __restrict__ wshuf, int* __restrict__ cursors,
                            int* __restrict__ perm) {
    int blk = blockIdx.x;
    if (blk < 256) {
        int t = blk * 256 + threadIdx.x;      // 0..65535
        int lane = t & 63;
        int kt = (t >> 6) & 7;
        int nt = (t >> 9) & 3;
        int s  = (t >> 11) & 7;
        int e  = (t >> 14) & 3;
        int kbase = kt * 16 + ((lane >> 5) << 3);
        int n = nt * 32 + (lane & 31);
        const float* src = w + (size_t)e * W_STRIDE + (size_t)s * (U * V) + n;
        float sc = (s >= 4) ? 0.5f : 1.0f;
        __attribute__((aligned(16))) unsigned short o[8];
#pragma unroll
        for (int j = 0; j < 8; j++) o[j] = f2bf(src[(size_t)(kbase + j) * V] * sc);
        *(u32x4*)(wshuf + (size_t)t * 8) = *(const u32x4*)o;
    } else {
        __shared__ int lcnt[4], lbase[4];
        int tid = threadIdx.x;
        if (tid < 4) lcnt[tid] = 0;
        __syncthreads();
        int b = (blk - 256) * 256 + tid;   // < 32768
        int e = wid[b];
        int r = atomicAdd(&lcnt[e], 1);
        __syncthreads();
        if (tid < 4) lbase[tid] = atomicAdd(&cursors[tid], lcnt[tid]);
        __syncthreads();
        perm[e * NB + lbase[e] + r] = b;
    }
}

// ---------------------------------------------------------------------------
// gemm R6: barrier-free, no LDS, A gathered directly into registers.
// Block = 256 thr = 4 waves = 1 sorted 32-row tile (single expert).
// Wave w = kout (out block), all 128 out cols (4 f32x16 accs).
// K = 256: x-block kout (seg kout) ++ x-block (kout+3)&3 (seg +4, 0.5 folded).
// A: lane m0=lane&31 owns row perm[tbase+m0]; per k-tile it loads 8 consecutive
//    fp32 (two dwordx4, 32-B granule, L3-hot x) and converts f2bf in-reg.
//    A fragment: A[m0][k = kt*16 + (lane>>5)*8 + j].
// B: 4 coalesced dwordx4 per k-step from wshuf (1 MB, L2-hot).
// No __syncthreads anywhere; waves pipeline gather/MFMA/store independently.
// ---------------------------------------------------------------------------
__global__ __launch_bounds__(256, 3) void gemm_kernel(
        const float* __restrict__ x, const unsigned short* __restrict__ wshuf,
        const int* __restrict__ cursors, const int* __restrict__ perm,
        float* __restrict__ out) {
    int c0 = cursors[0], c1 = cursors[1], c2 = cursors[2], c3 = cursors[3];
    int g = blockIdx.x;
    int e, rows, tbase;
    tile_map(g, c0, c1, c2, c3, e, rows, tbase);
    if (e < 0) return;

    const int t = threadIdx.x;
    const int kout = t >> 6;        // wave id = out block
    const int lane = t & 63;
    const int m0 = lane & 31;
    const int hi8 = (lane >> 5) << 3;

    const bool val = (m0 < rows);
    const int row_g = val ? perm[tbase + m0] : 0;
    const float* xrow = x + (size_t)row_g * IN_STRIDE;

    f32x16 acc0 = {}, acc1 = {}, acc2 = {}, acc3 = {};

    const int xb0 = kout, sg0 = kout;
    const int xb1 = (kout + 3) & 3, sg1 = xb1 + 4;
    int xbs[2] = {xb0, xb1};
    int sgs[2] = {sg0, sg1};

#pragma unroll
    for (int c = 0; c < 2; c++) {
        const unsigned short* wbase = wshuf + (size_t)(e * 8 + sgs[c]) * 16384;
        const float* xa = xrow + xbs[c] * 128 + hi8;
#pragma unroll
        for (int kt = 0; kt < 8; kt++) {
            // ---- A: direct gather + convert ----
            float4 v0 = *(const float4*)(xa + kt * 16);
            float4 v1 = *(const float4*)(xa + kt * 16 + 4);
            __attribute__((aligned(16))) unsigned short ah[8];
            ah[0] = f2bf(v0.x); ah[1] = f2bf(v0.y); ah[2] = f2bf(v0.z); ah[3] = f2bf(v0.w);
            ah[4] = f2bf(v1.x); ah[5] = f2bf(v1.y); ah[6] = f2bf(v1.z); ah[7] = f2bf(v1.w);
            bf16x8 a = __builtin_bit_cast(bf16x8, *(const u32x4*)ah);
            // ---- B: coalesced fragment loads ----
            bf16x8 b0 = __builtin_bit_cast(bf16x8,
                *(const u32x4*)(wbase + ((size_t)(0 * 8 + kt) * 64 + lane) * 8));
            bf16x8 b1 = __builtin_bit_cast(bf16x8,
                *(const u32x4*)(wbase + ((size_t)(1 * 8 + kt) * 64 + lane) * 8));
            bf16x8 b2 = __builtin_bit_cast(bf16x8,
                *(const u32x4*)(wbase + ((size_t)(2 * 8 + kt) * 64 + lane) * 8));
            bf16x8 b3 = __builtin_bit_cast(bf16x8,
                *(const u32x4*)(wbase + ((size_t)(3 * 8 + kt) * 64 + lane) * 8));
            acc0 = __builtin_amdgcn_mfma_f32_32x32x16_bf16(a, b0, acc0, 0, 0, 0);
            acc1 = __builtin_amdgcn_mfma_f32_32x32x16_bf16(a, b1, acc1, 0, 0, 0);
            acc2 = __builtin_amdgcn_mfma_f32_32x32x16_bf16(a, b2, acc2, 0, 0, 0);
            acc3 = __builtin_amdgcn_mfma_f32_32x32x16_bf16(a, b3, acc3, 0, 0, 0);
        }
    }

    // epilogue: C/D layout col=lane&31, row=(reg&3)+8*(reg>>2)+4*(lane>>5)
    const int rh = (lane >> 5) << 2;
    const int colb = kout * 128 + m0;
#pragma unroll
    for (int q = 0; q < 4; q++) {
#pragma unroll
        for (int d = 0; d < 4; d++) {
            int rl = d + 8 * q + rh;
            if (rl < rows) {
                int rg = perm[tbase + rl];
                float* o = out + (size_t)rg * OUT_STRIDE + colb;
                int reg = q * 4 + d;
                o[0]  = acc0[reg];
                o[32] = acc1[reg];
                o[64] = acc2[reg];
                o[96] = acc3[reg];
            }
        }
    }
}

extern "C" void kernel_launch(void* const* d_in, const int* in_sizes, int n_in,
                              void* d_out, int out_size, void* d_ws, size_t ws_size,
                              hipStream_t stream) {
    const float* x = (const float*)d_in[0];
    const float* w = (const float*)d_in[1];
    const int* wid = (const int*)d_in[2];
    float* out = (float*)d_out;

    char* ws = (char*)d_ws;
    unsigned short* wshuf = (unsigned short*)(ws + WS_WSHUF);
    int* perm = (int*)(ws + WS_PERM);
    int* cursors = (int*)(ws + WS_CURS);

    hipMemsetAsync(cursors, 0, 16, stream);
    prep_kernel<<<384, 256, 0, stream>>>(w, wid, wshuf, cursors, perm);
    gemm_kernel<<<MAXTILES, 256, 0, stream>>>(x, wshuf, cursors, perm, out);
}